// Round 1
// baseline (220.769 us; speedup 1.0000x reference)
//
#include <hip/hip_runtime.h>
#include <math.h>

#define IMG 224
#define NR  21   // 7 pool windows x 3 kernel shifts -> distinct clipped ranges per axis

__device__ __forceinline__ void range_lohi(int r, int& lo, int& hi) {
    int py = r / 3, s = (r % 3) - 1;     // shift = ky-1 in {-1,0,1}
    lo = 32 * py + s; hi = lo + 32;
    if (lo < 0) lo = 0;
    if (hi > IMG) hi = IMG;
}

// ---------------- K0: build tables -------------------------------------------
// blocks 0..20: Atab[r][y] = sum_{u in range r} cis(-2*pi*u*y/224)   (fp64 acc)
// block 21:     afold[r][j] = sum_{y in range r} ResizeWeight(y, j)  (fp64)
// block 22:     Dm (ortho DCT-II 8x8), wsum3 = sum_cin dct_w
__global__ void k0_setup(const float* __restrict__ dct_w,
                         float2* __restrict__ Atab, float* __restrict__ afold,
                         float* __restrict__ Dm, float* __restrict__ wsum3)
{
    __shared__ double c0[IMG], s0[IMG];
    int t = threadIdx.x;
    int blk = blockIdx.x;
    if (blk < NR) {
        if (t < IMG) {
            double ang = -2.0 * M_PI * (double)t / (double)IMG;
            c0[t] = cos(ang); s0[t] = sin(ang);
        }
        __syncthreads();
        int lo, hi; range_lohi(blk, lo, hi);
        if (t < IMG) {
            int y = t;
            double sr = 0.0, si = 0.0;
            for (int u = lo; u < hi; ++u) {
                int k = (u * y) % IMG;      // exact phase reduction
                sr += c0[k]; si += s0[k];
            }
            Atab[blk * IMG + y] = make_float2((float)sr, (float)si);
        }
    } else if (blk == NR) {
        for (int i = t; i < NR * 8; i += blockDim.x) {
            int r = i / 8, j = i % 8;
            int lo, hi; range_lohi(r, lo, hi);
            double s = 0.0;
            for (int y = lo; y < hi; ++y) {
                double sf = (y + 0.5) / 28.0 - 0.5;      // jax half-pixel sample
                double w = 1.0 - fabs(sf - (double)j);
                if (w < 0.0) w = 0.0;
                double tot = 0.0;
                for (int jj = 0; jj < 8; ++jj) {
                    double wj = 1.0 - fabs(sf - (double)jj);
                    if (wj > 0.0) tot += wj;             // boundary renorm = edge clamp
                }
                s += w / tot;
            }
            afold[i] = (float)s;
        }
    } else {
        if (t < 64) {
            int k = t / 8, m = t % 8;
            double v = cos(M_PI * (2.0 * m + 1.0) * k / 16.0) * 0.5;  // sqrt(2/8)=0.5
            if (k == 0) v *= 0.70710678118654752440;
            Dm[t] = (float)v;
        }
        for (int i = t; i < 64 * 9; i += blockDim.x) {
            int cout = i / 9, q = i % 9;
            float s = 0.f;
            for (int cin = 0; cin < 3; ++cin) s += dct_w[(cout * 3 + cin) * 9 + q];
            wsum3[i] = s;
        }
    }
}

// ---------------- K1: gray mean-block sums -----------------------------------
// meansum[b][j][k] = sum over 27x27 block grid of gray(8by+j, 8bx+k), gray = 255*RGB mix
__global__ void k1_meanblock(const float* __restrict__ x, float* __restrict__ meansum)
{
    int b = blockIdx.x >> 3, j = blockIdx.x & 7;
    int t = threadIdx.x;
    __shared__ float sm[216];
    if (t < 216) {
        const float* pr = x + (size_t)(b * 3 + 0) * IMG * IMG;
        const float* pg = x + (size_t)(b * 3 + 1) * IMG * IMG;
        const float* pb = x + (size_t)(b * 3 + 2) * IMG * IMG;
        float acc = 0.f;
        for (int by = 0; by < 27; ++by) {
            int o = (8 * by + j) * IMG + t;
            acc += 76.245f * pr[o] + 149.685f * pg[o] + 29.07f * pb[o];  // 255*(.299,.587,.114)
        }
        sm[t] = acc;
    }
    __syncthreads();
    if (t < 8) {
        float s = 0.f;
        for (int q = t; q < 216; q += 8) s += sm[q];   // column x === t (mod 8)
        meansum[(b * 8 + j) * 8 + t] = s;
    }
}

// ---------------- K2: dct_img + dct rect-sums --------------------------------
__global__ void k2_dct(const float* __restrict__ meansum, const float* __restrict__ Dm,
                       const float* __restrict__ afold, float* __restrict__ wsdct)
{
    int b = blockIdx.x, t = threadIdx.x;
    __shared__ float M[64], dimg[64], af[NR * 8], Ds[64];
    if (t < 64) { M[t] = meansum[b * 64 + t] * (1.0f / 729.0f); Ds[t] = Dm[t]; }
    if (t < NR * 8) af[t] = afold[t];
    __syncthreads();
    if (t < 64) {                       // dimg = D * M * D^T
        int i = t / 8, l = t % 8;
        float s = 0.f;
        for (int j = 0; j < 8; ++j) {
            float rj = 0.f;
            for (int k = 0; k < 8; ++k) rj += M[j * 8 + k] * Ds[l * 8 + k];
            s += Ds[i * 8 + j] * rj;
        }
        dimg[t] = s;
    }
    __syncthreads();
    for (int p = t; p < NR * NR; p += blockDim.x) {   // a_rr^T * dimg * a_cc
        int rr = p / NR, cc = p % NR;
        float s = 0.f;
        for (int j = 0; j < 8; ++j) {
            float rj = 0.f;
            for (int k = 0; k < 8; ++k) rj += dimg[j * 8 + k] * af[cc * 8 + k];
            s += af[rr * 8 + j] * rj;
        }
        wsdct[b * NR * NR + p] = s;
    }
}

// ---------------- K3: DFT rectangle-sum contraction --------------------------
// One block per (b, cin, 16-row slice). T[cc][y] = sum_x img[y,x]*A[cc][x];
// partial RS[rr][cc] += sum_{y in slice} A[rr][y]*T[cc][y] (complex).
__global__ __launch_bounds__(256) void k3_dft(const float* __restrict__ x,
        const float2* __restrict__ Atab, float2* __restrict__ rspart)
{
    int u = blockIdx.x;
    int slice = u % 14;
    int bc = u / 14;                 // b*3 + cin
    int t = threadIdx.x;
    __shared__ float  simg[16 * 228];      // stride 228: 16B-aligned rows, 2-way-max banks
    __shared__ float2 sA[NR * 225];        // stride 225: distinct banks across cc
    __shared__ float2 sT[NR * 17];

    const float* src = x + (size_t)bc * IMG * IMG + (size_t)slice * 16 * IMG;
    for (int i = t; i < 16 * 56; i += 256) {
        int y = i / 56, xi = (i % 56) * 4;
        float4 v = *(const float4*)(src + y * IMG + xi);
        *(float4*)&simg[y * 228 + xi] = v;
    }
    for (int i = t; i < NR * IMG; i += 256) {
        int r = i / IMG, xx = i % IMG;
        sA[r * 225 + xx] = Atab[i];
    }
    __syncthreads();

    for (int w = t; w < NR * 16; w += 256) {     // phase B: 21cc x 16y units
        int y = w & 15, cc = w >> 4;
        float tr = 0.f, ti = 0.f;
        const float*  row  = &simg[y * 228];
        const float2* arow = &sA[cc * 225];
        for (int xx = 0; xx < IMG; xx += 4) {
            float4 iv = *(const float4*)(row + xx);
            float2 a0 = arow[xx + 0], a1 = arow[xx + 1];
            float2 a2 = arow[xx + 2], a3 = arow[xx + 3];
            tr += iv.x * a0.x + iv.y * a1.x + iv.z * a2.x + iv.w * a3.x;
            ti += iv.x * a0.y + iv.y * a1.y + iv.z * a2.y + iv.w * a3.y;
        }
        sT[cc * 17 + y] = make_float2(tr, ti);
    }
    __syncthreads();

    int y0 = slice * 16;
    for (int p = t; p < NR * NR; p += 256) {     // phase C
        int rr = p / NR, cc = p % NR;
        float re = 0.f, im = 0.f;
        for (int yy = 0; yy < 16; ++yy) {
            float2 a  = sA[rr * 225 + y0 + yy];
            float2 tv = sT[cc * 17 + yy];
            re += a.x * tv.x - a.y * tv.y;
            im += a.x * tv.y + a.y * tv.x;
        }
        rspart[(size_t)u * NR * NR + p] = make_float2(re, im);
    }
}

// ---------------- K4: assemble pooled features P^T[6272][32] -----------------
__global__ void k4_assemble(const float2* __restrict__ rspart, const float* __restrict__ wsdct,
        const float* __restrict__ wsum3, const float* __restrict__ dct_b,
        const float* __restrict__ fft_w, const float* __restrict__ fft_b,
        float* __restrict__ PT)
{
    int b = blockIdx.x, t = threadIdx.x;
    __shared__ float2 RSs[3 * NR * NR];
    __shared__ float  WSd[NR * NR];
    for (int i = t; i < 3 * NR * NR; i += 256) {
        int cin = i / (NR * NR), p = i % (NR * NR);
        float2 s = make_float2(0.f, 0.f);
        for (int sl = 0; sl < 14; ++sl) {
            float2 v = rspart[((size_t)(b * 3 + cin) * 14 + sl) * NR * NR + p];
            s.x += v.x; s.y += v.y;
        }
        RSs[i] = s;
    }
    for (int p = t; p < NR * NR; p += 256) WSd[p] = wsdct[b * NR * NR + p];
    __syncthreads();

    const float inv = 1.0f / 1024.0f;
    for (int i = t; i < 3136; i += 256) {        // DCT half
        int cout = i / 49, q = i % 49, py = q / 7, px = q % 7;
        float s = 0.f;
        #pragma unroll
        for (int ky = 0; ky < 3; ++ky)
            #pragma unroll
            for (int kx = 0; kx < 3; ++kx)
                s += wsum3[cout * 9 + ky * 3 + kx] * WSd[(py * 3 + ky) * NR + (px * 3 + kx)];
        PT[(size_t)i * 32 + b] = dct_b[cout] + s * inv;
    }
    for (int i = t; i < 3136; i += 256) {        // FFT half
        int cout = i / 49, q = i % 49, py = q / 7, px = q % 7;
        float s = 0.f;
        for (int cin = 0; cin < 3; ++cin) {
            #pragma unroll
            for (int ky = 0; ky < 3; ++ky)
                #pragma unroll
                for (int kx = 0; kx < 3; ++kx) {
                    float2 v = RSs[cin * NR * NR + (py * 3 + ky) * NR + (px * 3 + kx)];
                    const float* wp = fft_w + ((cout * 6 + 2 * cin) * 9 + ky * 3 + kx);
                    s += wp[0] * v.x + wp[9] * v.y;   // real chan, imag chan
                }
        }
        PT[(size_t)(3136 + i) * 32 + b] = fft_b[cout] + s * inv;
    }
}

// ---------------- K5: FC partials (16-way k-split) ---------------------------
__global__ __launch_bounds__(256) void k5_fc(const float* __restrict__ PT,
        const float* __restrict__ fc_w, float* __restrict__ fcpart)
{
    int ot = blockIdx.x & 15, kc = blockIdx.x >> 4;
    int t = threadIdx.x;
    int b = t & 31, oi = t >> 5;
    int o0 = ot * 32 + oi * 4;
    float a0 = 0.f, a1 = 0.f, a2 = 0.f, a3 = 0.f;
    const float* w0 = fc_w + (size_t)(o0 + 0) * 6272;
    const float* w1 = fc_w + (size_t)(o0 + 1) * 6272;
    const float* w2 = fc_w + (size_t)(o0 + 2) * 6272;
    const float* w3 = fc_w + (size_t)(o0 + 3) * 6272;
    int k0 = kc * 392;
    for (int k = k0; k < k0 + 392; ++k) {
        float p = PT[(size_t)k * 32 + b];
        a0 += p * w0[k]; a1 += p * w1[k]; a2 += p * w2[k]; a3 += p * w3[k];
    }
    fcpart[((size_t)kc * 512 + o0 + 0) * 32 + b] = a0;
    fcpart[((size_t)kc * 512 + o0 + 1) * 32 + b] = a1;
    fcpart[((size_t)kc * 512 + o0 + 2) * 32 + b] = a2;
    fcpart[((size_t)kc * 512 + o0 + 3) * 32 + b] = a3;
}

// ---------------- K6: reduce + bias + relu -----------------------------------
__global__ void k6_out(const float* __restrict__ fcpart, const float* __restrict__ fc_b,
                       float* __restrict__ out)
{
    int idx = blockIdx.x * 256 + threadIdx.x;
    if (idx < 32 * 512) {
        int b = idx >> 9, o = idx & 511;
        float s = fc_b[o];
        for (int c = 0; c < 16; ++c) s += fcpart[((size_t)c * 512 + o) * 32 + b];
        out[(size_t)b * 512 + o] = fmaxf(s, 0.f);
    }
}

extern "C" void kernel_launch(void* const* d_in, const int* in_sizes, int n_in,
                              void* d_out, int out_size, void* d_ws, size_t ws_size,
                              hipStream_t stream)
{
    const float* x     = (const float*)d_in[0];
    const float* dct_w = (const float*)d_in[1];
    const float* dct_b = (const float*)d_in[2];
    const float* fft_w = (const float*)d_in[3];
    const float* fft_b = (const float*)d_in[4];
    const float* fc_w  = (const float*)d_in[5];
    const float* fc_b  = (const float*)d_in[6];
    float* out = (float*)d_out;

    char* ws = (char*)d_ws;
    size_t off = 0;
    auto alloc = [&](size_t bytes) {
        char* p = ws + off;
        off = (off + bytes + 255) & ~(size_t)255;
        return p;
    };
    float2* Atab    = (float2*)alloc((size_t)NR * IMG * 8);        // 37.6 KB
    float*  afold   = (float*) alloc((size_t)NR * 8 * 4);
    float*  Dm      = (float*) alloc(64 * 4);
    float*  wsum3   = (float*) alloc(64 * 9 * 4);
    float*  meansum = (float*) alloc(32 * 64 * 4);
    float*  wsdct   = (float*) alloc((size_t)32 * NR * NR * 4);    // 56 KB
    float2* rspart  = (float2*)alloc((size_t)96 * 14 * NR * NR * 8); // 4.74 MB
    float*  PT      = (float*) alloc((size_t)6272 * 32 * 4);       // 803 KB
    float*  fcpart  = (float*) alloc((size_t)16 * 512 * 32 * 4);   // 1 MB
    (void)ws_size; (void)in_sizes; (void)n_in; (void)out_size;

    hipLaunchKernelGGL(k0_setup,    dim3(23),   dim3(256), 0, stream, dct_w, Atab, afold, Dm, wsum3);
    hipLaunchKernelGGL(k1_meanblock,dim3(256),  dim3(256), 0, stream, x, meansum);
    hipLaunchKernelGGL(k2_dct,      dim3(32),   dim3(256), 0, stream, meansum, Dm, afold, wsdct);
    hipLaunchKernelGGL(k3_dft,      dim3(1344), dim3(256), 0, stream, x, Atab, rspart);
    hipLaunchKernelGGL(k4_assemble, dim3(32),   dim3(256), 0, stream, rspart, wsdct, wsum3, dct_b, fft_w, fft_b, PT);
    hipLaunchKernelGGL(k5_fc,       dim3(256),  dim3(256), 0, stream, PT, fc_w, fcpart);
    hipLaunchKernelGGL(k6_out,      dim3(64),   dim3(256), 0, stream, fcpart, fc_b, out);
}

// Round 2
// 183.475 us; speedup vs baseline: 1.2033x; 1.2033x over previous
//
#include <hip/hip_runtime.h>
#include <math.h>

#define IMG 224
#define NR  21   // 7 pool windows x 3 kernel shifts -> distinct clipped ranges per axis

__device__ __forceinline__ void range_lohi(int r, int& lo, int& hi) {
    int py = r / 3, s = (r % 3) - 1;     // shift = ky-1 in {-1,0,1}
    lo = 32 * py + s; hi = lo + 32;
    if (lo < 0) lo = 0;
    if (hi > IMG) hi = IMG;
}

// ---------------- K0: build tables -------------------------------------------
__global__ void k0_setup(const float* __restrict__ dct_w,
                         float2* __restrict__ Atab, float* __restrict__ afold,
                         float* __restrict__ Dm, float* __restrict__ wsum3)
{
    __shared__ double c0[IMG], s0[IMG];
    int t = threadIdx.x;
    int blk = blockIdx.x;
    if (blk < NR) {
        if (t < IMG) {
            double ang = -2.0 * M_PI * (double)t / (double)IMG;
            c0[t] = cos(ang); s0[t] = sin(ang);
        }
        __syncthreads();
        int lo, hi; range_lohi(blk, lo, hi);
        if (t < IMG) {
            int y = t;
            double sr = 0.0, si = 0.0;
            for (int u = lo; u < hi; ++u) {
                int k = (u * y) % IMG;      // exact phase reduction
                sr += c0[k]; si += s0[k];
            }
            Atab[blk * IMG + y] = make_float2((float)sr, (float)si);
        }
    } else if (blk == NR) {
        for (int i = t; i < NR * 8; i += blockDim.x) {
            int r = i / 8, j = i % 8;
            int lo, hi; range_lohi(r, lo, hi);
            double s = 0.0;
            for (int y = lo; y < hi; ++y) {
                double sf = (y + 0.5) / 28.0 - 0.5;      // jax half-pixel sample
                double w = 1.0 - fabs(sf - (double)j);
                if (w < 0.0) w = 0.0;
                double tot = 0.0;
                for (int jj = 0; jj < 8; ++jj) {
                    double wj = 1.0 - fabs(sf - (double)jj);
                    if (wj > 0.0) tot += wj;             // boundary renorm = edge clamp
                }
                s += w / tot;
            }
            afold[i] = (float)s;
        }
    } else {
        if (t < 64) {
            int k = t / 8, m = t % 8;
            double v = cos(M_PI * (2.0 * m + 1.0) * k / 16.0) * 0.5;  // sqrt(2/8)=0.5
            if (k == 0) v *= 0.70710678118654752440;
            Dm[t] = (float)v;
        }
        for (int i = t; i < 64 * 9; i += blockDim.x) {
            int cout = i / 9, q = i % 9;
            float s = 0.f;
            for (int cin = 0; cin < 3; ++cin) s += dct_w[(cout * 3 + cin) * 9 + q];
            wsum3[i] = s;
        }
    }
}

// ---------------- K1: gray mean-block sums -----------------------------------
__global__ void k1_meanblock(const float* __restrict__ x, float* __restrict__ meansum)
{
    int b = blockIdx.x >> 3, j = blockIdx.x & 7;
    int t = threadIdx.x;
    __shared__ float sm[216];
    if (t < 216) {
        const float* pr = x + (size_t)(b * 3 + 0) * IMG * IMG;
        const float* pg = x + (size_t)(b * 3 + 1) * IMG * IMG;
        const float* pb = x + (size_t)(b * 3 + 2) * IMG * IMG;
        float acc = 0.f;
        for (int by = 0; by < 27; ++by) {
            int o = (8 * by + j) * IMG + t;
            acc += 76.245f * pr[o] + 149.685f * pg[o] + 29.07f * pb[o];  // 255*(.299,.587,.114)
        }
        sm[t] = acc;
    }
    __syncthreads();
    if (t < 8) {
        float s = 0.f;
        for (int q = t; q < 216; q += 8) s += sm[q];   // column x === t (mod 8)
        meansum[(b * 8 + j) * 8 + t] = s;
    }
}

// ---------------- K2: dct_img + dct rect-sums --------------------------------
__global__ void k2_dct(const float* __restrict__ meansum, const float* __restrict__ Dm,
                       const float* __restrict__ afold, float* __restrict__ wsdct)
{
    int b = blockIdx.x, t = threadIdx.x;
    __shared__ float M[64], dimg[64], af[NR * 8], Ds[64];
    if (t < 64) { M[t] = meansum[b * 64 + t] * (1.0f / 729.0f); Ds[t] = Dm[t]; }
    if (t < NR * 8) af[t] = afold[t];
    __syncthreads();
    if (t < 64) {                       // dimg = D * M * D^T
        int i = t / 8, l = t % 8;
        float s = 0.f;
        for (int j = 0; j < 8; ++j) {
            float rj = 0.f;
            for (int k = 0; k < 8; ++k) rj += M[j * 8 + k] * Ds[l * 8 + k];
            s += Ds[i * 8 + j] * rj;
        }
        dimg[t] = s;
    }
    __syncthreads();
    for (int p = t; p < NR * NR; p += blockDim.x) {   // a_rr^T * dimg * a_cc
        int rr = p / NR, cc = p % NR;
        float s = 0.f;
        for (int j = 0; j < 8; ++j) {
            float rj = 0.f;
            for (int k = 0; k < 8; ++k) rj += dimg[j * 8 + k] * af[cc * 8 + k];
            s += af[rr * 8 + j] * rj;
        }
        wsdct[b * NR * NR + p] = s;
    }
}

// ---------------- K3a: row transform T[row][cc] = sum_x img[row,x]*A_cc(x) ---
// 336 blocks x 256 thr. Block = 64 rows; wave w = x-part w (56 x each).
// Each lane owns one row and all 21 complex accumulators; A reads are
// wave-uniform LDS broadcasts (conflict-free), img reads are direct global.
__global__ __launch_bounds__(256) void k3a_rowdft(const float* __restrict__ x,
        const float2* __restrict__ Atab, float2* __restrict__ T)
{
    int t = threadIdx.x;
    int part = t >> 6;                  // wave id = x-part 0..3
    int lane = t & 63;                  // row within block
    __shared__ float2 sA[NR * IMG];     // 37.6 KB; reused as reduction buffer

    for (int i = t; i < NR * IMG; i += 256) sA[i] = Atab[i];
    __syncthreads();

    int row = blockIdx.x * 64 + lane;   // [0, 21504)
    const float* src = x + (size_t)row * IMG + part * 56;

    float2 acc[NR];
    #pragma unroll
    for (int c = 0; c < NR; ++c) acc[c] = make_float2(0.f, 0.f);

    for (int i = 0; i < 56; i += 4) {
        float4 v = *(const float4*)(src + i);
        #pragma unroll
        for (int c = 0; c < NR; ++c) {
            const float2* ap = &sA[c * IMG + part * 56 + i];   // wave-uniform addr
            float2 a0 = ap[0], a1 = ap[1], a2 = ap[2], a3 = ap[3];
            acc[c].x += v.x * a0.x + v.y * a1.x + v.z * a2.x + v.w * a3.x;
            acc[c].y += v.x * a0.y + v.y * a1.y + v.z * a2.y + v.w * a3.y;
        }
    }

    __syncthreads();                    // everyone done reading sA
    float2* red = sA;                   // 3*64*21 = 4032 float2 fits in 4704
    if (part > 0) {
        float2* dst = red + ((size_t)(part - 1) * 64 + lane) * NR;
        #pragma unroll
        for (int c = 0; c < NR; ++c) dst[c] = acc[c];
    }
    __syncthreads();
    if (part == 0) {
        #pragma unroll
        for (int c = 0; c < NR; ++c) {
            float2 s = acc[c];
            float2 p1 = red[((size_t)0 * 64 + lane) * NR + c];
            float2 p2 = red[((size_t)1 * 64 + lane) * NR + c];
            float2 p3 = red[((size_t)2 * 64 + lane) * NR + c];
            s.x += p1.x + p2.x + p3.x;
            s.y += p1.y + p2.y + p3.y;
            T[(size_t)row * NR + c] = s;
        }
    }
}

// ---------------- K3b: column fold RS[rr][cc] = sum_y A_rr(y)*T[y][cc] -------
// 192 blocks: (bc 0..95) x (y-half 0..1). Both operands staged in LDS (37.6 KB).
__global__ __launch_bounds__(256) void k3b_colfold(const float2* __restrict__ T,
        const float2* __restrict__ Atab, float2* __restrict__ rs2)
{
    int blk = blockIdx.x;
    int bc = blk >> 1, half = blk & 1;
    int t = threadIdx.x;
    __shared__ float2 sT[112 * NR];     // [y_local][cc]
    __shared__ float2 sAh[NR * 112];    // [rr][y_local]

    const float2* Tbase = T + ((size_t)bc * IMG + half * 112) * NR;
    for (int i = t; i < 112 * NR; i += 256) sT[i] = Tbase[i];
    for (int i = t; i < NR * 112; i += 256) {
        int rr = i / 112, y = i % 112;
        sAh[i] = Atab[rr * IMG + half * 112 + y];
    }
    __syncthreads();

    for (int p = t; p < NR * NR; p += 256) {
        int rr = p / NR, cc = p % NR;
        float re = 0.f, im = 0.f;
        const float2* arow = &sAh[rr * 112];
        for (int y = 0; y < 112; ++y) {
            float2 a  = arow[y];
            float2 tv = sT[y * NR + cc];
            re += a.x * tv.x - a.y * tv.y;
            im += a.x * tv.y + a.y * tv.x;
        }
        rs2[(size_t)blk * NR * NR + p] = make_float2(re, im);
    }
}

// ---------------- K4: assemble pooled features P^T[6272][32] -----------------
__global__ void k4_assemble(const float2* __restrict__ rs2, const float* __restrict__ wsdct,
        const float* __restrict__ wsum3, const float* __restrict__ dct_b,
        const float* __restrict__ fft_w, const float* __restrict__ fft_b,
        float* __restrict__ PT)
{
    int b = blockIdx.x, t = threadIdx.x;
    __shared__ float2 RSs[3 * NR * NR];
    __shared__ float  WSd[NR * NR];
    for (int i = t; i < 3 * NR * NR; i += 256) {
        int cin = i / (NR * NR), p = i % (NR * NR);
        float2 v0 = rs2[((size_t)((b * 3 + cin) * 2 + 0)) * NR * NR + p];
        float2 v1 = rs2[((size_t)((b * 3 + cin) * 2 + 1)) * NR * NR + p];
        RSs[i] = make_float2(v0.x + v1.x, v0.y + v1.y);
    }
    for (int p = t; p < NR * NR; p += 256) WSd[p] = wsdct[b * NR * NR + p];
    __syncthreads();

    const float inv = 1.0f / 1024.0f;
    for (int i = t; i < 3136; i += 256) {        // DCT half
        int cout = i / 49, q = i % 49, py = q / 7, px = q % 7;
        float s = 0.f;
        #pragma unroll
        for (int ky = 0; ky < 3; ++ky)
            #pragma unroll
            for (int kx = 0; kx < 3; ++kx)
                s += wsum3[cout * 9 + ky * 3 + kx] * WSd[(py * 3 + ky) * NR + (px * 3 + kx)];
        PT[(size_t)i * 32 + b] = dct_b[cout] + s * inv;
    }
    for (int i = t; i < 3136; i += 256) {        // FFT half
        int cout = i / 49, q = i % 49, py = q / 7, px = q % 7;
        float s = 0.f;
        for (int cin = 0; cin < 3; ++cin) {
            #pragma unroll
            for (int ky = 0; ky < 3; ++ky)
                #pragma unroll
                for (int kx = 0; kx < 3; ++kx) {
                    float2 v = RSs[cin * NR * NR + (py * 3 + ky) * NR + (px * 3 + kx)];
                    const float* wp = fft_w + ((cout * 6 + 2 * cin) * 9 + ky * 3 + kx);
                    s += wp[0] * v.x + wp[9] * v.y;   // real chan, imag chan
                }
        }
        PT[(size_t)(3136 + i) * 32 + b] = fft_b[cout] + s * inv;
    }
}

// ---------------- K5: FC partials (16-way k-split) ---------------------------
__global__ __launch_bounds__(256) void k5_fc(const float* __restrict__ PT,
        const float* __restrict__ fc_w, float* __restrict__ fcpart)
{
    int ot = blockIdx.x & 15, kc = blockIdx.x >> 4;
    int t = threadIdx.x;
    int b = t & 31, oi = t >> 5;
    int o0 = ot * 32 + oi * 4;
    float a0 = 0.f, a1 = 0.f, a2 = 0.f, a3 = 0.f;
    const float* w0 = fc_w + (size_t)(o0 + 0) * 6272;
    const float* w1 = fc_w + (size_t)(o0 + 1) * 6272;
    const float* w2 = fc_w + (size_t)(o0 + 2) * 6272;
    const float* w3 = fc_w + (size_t)(o0 + 3) * 6272;
    int k0 = kc * 392;
    for (int k = k0; k < k0 + 392; ++k) {
        float p = PT[(size_t)k * 32 + b];
        a0 += p * w0[k]; a1 += p * w1[k]; a2 += p * w2[k]; a3 += p * w3[k];
    }
    fcpart[((size_t)kc * 512 + o0 + 0) * 32 + b] = a0;
    fcpart[((size_t)kc * 512 + o0 + 1) * 32 + b] = a1;
    fcpart[((size_t)kc * 512 + o0 + 2) * 32 + b] = a2;
    fcpart[((size_t)kc * 512 + o0 + 3) * 32 + b] = a3;
}

// ---------------- K6: reduce + bias + relu -----------------------------------
__global__ void k6_out(const float* __restrict__ fcpart, const float* __restrict__ fc_b,
                       float* __restrict__ out)
{
    int idx = blockIdx.x * 256 + threadIdx.x;
    if (idx < 32 * 512) {
        int b = idx >> 9, o = idx & 511;
        float s = fc_b[o];
        for (int c = 0; c < 16; ++c) s += fcpart[((size_t)c * 512 + o) * 32 + b];
        out[(size_t)b * 512 + o] = fmaxf(s, 0.f);
    }
}

extern "C" void kernel_launch(void* const* d_in, const int* in_sizes, int n_in,
                              void* d_out, int out_size, void* d_ws, size_t ws_size,
                              hipStream_t stream)
{
    const float* x     = (const float*)d_in[0];
    const float* dct_w = (const float*)d_in[1];
    const float* dct_b = (const float*)d_in[2];
    const float* fft_w = (const float*)d_in[3];
    const float* fft_b = (const float*)d_in[4];
    const float* fc_w  = (const float*)d_in[5];
    const float* fc_b  = (const float*)d_in[6];
    float* out = (float*)d_out;

    char* ws = (char*)d_ws;
    size_t off = 0;
    auto alloc = [&](size_t bytes) {
        char* p = ws + off;
        off = (off + bytes + 255) & ~(size_t)255;
        return p;
    };
    float2* Atab    = (float2*)alloc((size_t)NR * IMG * 8);        // 37.6 KB
    float*  afold   = (float*) alloc((size_t)NR * 8 * 4);
    float*  Dm      = (float*) alloc(64 * 4);
    float*  wsum3   = (float*) alloc(64 * 9 * 4);
    float*  meansum = (float*) alloc(32 * 64 * 4);
    float*  wsdct   = (float*) alloc((size_t)32 * NR * NR * 4);    // 56 KB
    float2* T       = (float2*)alloc((size_t)21504 * NR * 8);      // 3.61 MB
    float2* rs2     = (float2*)alloc((size_t)192 * NR * NR * 8);   // 677 KB
    float*  PT      = (float*) alloc((size_t)6272 * 32 * 4);       // 803 KB
    float*  fcpart  = (float*) alloc((size_t)16 * 512 * 32 * 4);   // 1 MB
    (void)ws_size; (void)in_sizes; (void)n_in; (void)out_size;

    hipLaunchKernelGGL(k0_setup,    dim3(23),   dim3(256), 0, stream, dct_w, Atab, afold, Dm, wsum3);
    hipLaunchKernelGGL(k1_meanblock,dim3(256),  dim3(256), 0, stream, x, meansum);
    hipLaunchKernelGGL(k2_dct,      dim3(32),   dim3(256), 0, stream, meansum, Dm, afold, wsdct);
    hipLaunchKernelGGL(k3a_rowdft,  dim3(336),  dim3(256), 0, stream, x, Atab, T);
    hipLaunchKernelGGL(k3b_colfold, dim3(192),  dim3(256), 0, stream, T, Atab, rs2);
    hipLaunchKernelGGL(k4_assemble, dim3(32),   dim3(256), 0, stream, rs2, wsdct, wsum3, dct_b, fft_w, fft_b, PT);
    hipLaunchKernelGGL(k5_fc,       dim3(256),  dim3(256), 0, stream, PT, fc_w, fcpart);
    hipLaunchKernelGGL(k6_out,      dim3(64),   dim3(256), 0, stream, fcpart, fc_b, out);
}